// Round 9
// baseline (228.601 us; speedup 1.0000x reference)
//
#include <hip/hip_runtime.h>
#include <math.h>

#define NB   16      // batch
#define NM   4096    // preds per image
#define NT   512     // targets per image
#define CAP  16      // max candidates per row (overflow -> exact fallback)
#define IOU_THR 0.1f
#define EPSG 1e-7f
#define NROWS (NB*NM)
#define SENT 0xFFFFFFFFu

// ---------------------------------------------------------------------------
// Kernel 1: wave-per-row candidate build, targets staged in LDS per 64-row
// block. Ballot compaction, ascending-j order, transposed (e-major) storage
// so kernel-2's per-window register prefetch is coalesced.  (R8, measured.)
// ---------------------------------------------------------------------------
__global__ __launch_bounds__(256) void cand_kernel(
    const float4* __restrict__ pred, const float4* __restrict__ tgt,
    int* __restrict__ counts, float2* __restrict__ cands)
{
    __shared__ float4 t_lds[NT];
    const int rb = blockIdx.x * 64;          // 64 rows per block, same image
    const int b  = rb >> 12;                 // NM = 4096
    for (int i = threadIdx.x; i < NT; i += 256)
        t_lds[i] = tgt[b * NT + i];
    __syncthreads();

    const int wv = threadIdx.x >> 6, lane = threadIdx.x & 63;
    for (int rr = 0; rr < 16; ++rr) {
        const int row = rb + wv * 16 + rr;
        float4 p = pred[row];                // wave-uniform load
        float area_p = (p.z - p.x) * (p.w - p.y);
        int base = 0;
        #pragma unroll
        for (int pass = 0; pass < NT / 64; ++pass) {
            int j = (pass << 6) + lane;
            float4 t = t_lds[j];
            float area_t = (t.z - t.x) * (t.w - t.y);
            float w = fmaxf(fminf(p.z, t.z) - fmaxf(p.x, t.x), 0.f);
            float h = fmaxf(fminf(p.w, t.w) - fmaxf(p.y, t.y), 0.f);
            float inter = w * h;
            float uni   = (area_p + area_t) - inter;   // ref association
            float iou   = inter / uni;
            bool q = iou > IOU_THR;
            unsigned long long m = __ballot(q);
            if (q) {
                int off = base + __popcll(m & ((1ull << lane) - 1ull));
                if (off < CAP)
                    cands[(size_t)off * NROWS + row] = make_float2(iou, __int_as_float(j));
            }
            base += __popcll(m);
        }
        if (lane == 0) counts[row] = base;   // > CAP flags overflow
    }
}

// ---------------------------------------------------------------------------
// Kernel 2: ONE WAVE per image, lockstep windowed auction.
// Influence in the claim-auction flows strictly upward in row index, so
// ascending 64-row windows resolved to their internal fixed point are FINAL.
// No barriers in the loop (single wave); merged propose/settle (optimistic
// HOLD + top-of-loop recheck); candidates register-prefetched 1 window ahead;
// GIoU commit done once at the end, by target (claim[j]==r <=> r holds j).
// ---------------------------------------------------------------------------
__global__ __launch_bounds__(64) void wave_auction(
    const float4* __restrict__ pred, const float4* __restrict__ tgt,
    const int* __restrict__ counts, const float2* __restrict__ cands,
    float* __restrict__ per_img)
{
    __shared__ float4   t_lds[NT];   // 8 KB
    __shared__ unsigned claim[NT];   // 2 KB
    const int b = blockIdx.x, lane = threadIdx.x, gbase = b * NM;
    volatile unsigned* vclaim = claim;

    #pragma unroll
    for (int i = 0; i < NT / 64; ++i) {
        t_lds[i * 64 + lane] = tgt[b * NT + i * 64 + lane];
        claim[i * 64 + lane] = SENT;
    }
    __syncthreads();                 // single wave: cheap; orders LDS init

    // prefetch window 0 into registers
    int nN; float2 nC[CAP];
    {
        int row = gbase + lane;
        nN = counts[row];
        #pragma unroll
        for (int e = 0; e < CAP; ++e) nC[e] = cands[(size_t)e * NROWS + row];
    }

    for (int k = 0; k < NM / 64; ++k) {
        // rotate double buffer (first use waits the in-flight loads)
        int cN = nN;
        float2 cC[CAP];
        #pragma unroll
        for (int e = 0; e < CAP; ++e) cC[e] = nC[e];
        if (k + 1 < NM / 64) {       // issue next-window prefetch; hides under work
            int row = gbase + (k + 1) * 64 + lane;
            nN = counts[row];
            #pragma unroll
            for (int e = 0; e < CAP; ++e) nC[e] = cands[(size_t)e * NROWS + row];
        }
        const unsigned row = (unsigned)(k * 64 + lane);

        if (__builtin_expect((bool)__ballot(cN > CAP), 0)) {
            // ---- exact serial fallback for the whole window (~never) ----
            for (int r = 0; r < 64; ++r) {
                int rc = __shfl(cN, r);
                if (rc == 0) continue;
                unsigned rrow = (unsigned)(k * 64 + r);
                float4 p4 = pred[gbase + (int)rrow];      // uniform-address load
                float area_p = (p4.z - p4.x) * (p4.w - p4.y);
                float v = -1.f; int bj = NT;
                #pragma unroll
                for (int i = 0; i < NT / 64; ++i) {
                    int j = lane + i * 64;                // ascending j per lane
                    float4 tt = t_lds[j];
                    if (vclaim[j] > rrow) {
                        float area_t = (tt.z - tt.x) * (tt.w - tt.y);
                        float w = fmaxf(fminf(p4.z, tt.z) - fmaxf(p4.x, tt.x), 0.f);
                        float h = fmaxf(fminf(p4.w, tt.w) - fmaxf(p4.y, tt.y), 0.f);
                        float inter = w * h;
                        float iou = inter / ((area_p + area_t) - inter);
                        if (iou > v) { v = iou; bj = j; } // strict >: lowest j
                    }
                }
                #pragma unroll
                for (int off = 1; off < 64; off <<= 1) {
                    float ov = __shfl_xor(v, off);
                    int   oj = __shfl_xor(bj, off);
                    if (ov > v || (ov == v && oj < bj)) { v = ov; bj = oj; }
                }
                if (v > IOU_THR && lane == 0) atomicMin(&claim[bj], rrow);
            }
        } else {
            // ---- lockstep auction to window fixed point ----
            int stt = (cN > 0) ? 0 : 2;                   // 0=UNRES 1=HOLD 2=DONE
            int myj = -1;
            while (true) {
                if (stt == 1 && vclaim[myj] != row) stt = 0;   // sniped: rejoin
                if (!__ballot(stt == 0)) break;                // window final
                if (stt == 0) {
                    float bv = -1.f; int bj = -1;
                    #pragma unroll
                    for (int e = 0; e < CAP; ++e) {            // padded, branch-free
                        float2 ce = cC[e];
                        int j = __float_as_int(ce.y) & (NT - 1);
                        unsigned cj = vclaim[j];
                        if (e < cN && cj >= row && ce.x > bv) { bv = ce.x; bj = j; }
                    }
                    if (bj < 0) stt = 2;                       // invalid (permanent)
                    else {
                        atomicMin(&claim[bj], row);
                        myj = bj; stt = 1;                     // optimistic hold
                    }
                }
            }
        }
    }

    __syncthreads();                 // order claim[] ops before commit reads

    // ---- commit by target: claim[j]==r <=> r matched j (unique fixed point) ----
    float ls = 0.f, cs = 0.f;
    #pragma unroll
    for (int i = 0; i < NT / 64; ++i) {
        int j = i * 64 + lane;
        unsigned r = claim[j];
        if (r != SENT) {
            float4 p4 = pred[gbase + (int)r];
            float4 tt = t_lds[j];
            float inter = fmaxf(fminf(p4.z, tt.z) - fmaxf(p4.x, tt.x), 0.f) *
                          fmaxf(fminf(p4.w, tt.w) - fmaxf(p4.y, tt.y), 0.f);
            float area_p = (p4.z - p4.x) * (p4.w - p4.y);
            float area_t = (tt.z - tt.x) * (tt.w - tt.y);
            float uni = area_p + area_t - inter;
            float iou = inter / (uni + EPSG);
            float enc = (fmaxf(p4.z, tt.z) - fminf(p4.x, tt.x)) *
                        (fmaxf(p4.w, tt.w) - fminf(p4.y, tt.y));
            float giou = iou - (enc - uni) / (enc + EPSG);
            ls += 1.f - giou;
            cs += 1.f;
        }
    }
    #pragma unroll
    for (int off = 32; off >= 1; off >>= 1) {
        ls += __shfl_xor(ls, off);
        cs += __shfl_xor(cs, off);
    }
    if (lane == 0) per_img[b] = (cs > 0.f) ? ls / cs : 0.f;
}

// ---------------------------------------------------------------------------
// Kernel 3: mean over images -> scalar output. Deterministic (no atomics).
// ---------------------------------------------------------------------------
__global__ void reduce_kernel(const float* __restrict__ per_img,
                              float* __restrict__ out)
{
    if (threadIdx.x == 0 && blockIdx.x == 0) {
        float s = 0.f;
        for (int i = 0; i < NB; ++i) s += per_img[i];
        out[0] = s / (float)NB;
    }
}

extern "C" void kernel_launch(void* const* d_in, const int* in_sizes, int n_in,
                              void* d_out, int out_size, void* d_ws, size_t ws_size,
                              hipStream_t stream)
{
    const float4* pred = (const float4*)d_in[0];   // [16,4096,4] f32
    const float4* tgt  = (const float4*)d_in[1];   // [16,512,4]  f32

    char* ws = (char*)d_ws;
    // layout: counts [NROWS] i32 | cands [CAP*NROWS] float2 | per_img [NB] f32
    int*    counts  = (int*)ws;
    size_t  off1    = (size_t)NROWS * sizeof(int);                 // 256 KB
    float2* cands   = (float2*)(ws + off1);
    size_t  off2    = off1 + (size_t)CAP * NROWS * sizeof(float2); // +8 MB
    float*  per_img = (float*)(ws + off2);

    cand_kernel<<<NROWS / 64, 256, 0, stream>>>(pred, tgt, counts, cands);
    wave_auction<<<NB, 64, 0, stream>>>(pred, tgt, counts, cands, per_img);
    reduce_kernel<<<1, 64, 0, stream>>>(per_img, (float*)d_out);
}

// Round 10
// 74.055 us; speedup vs baseline: 3.0869x; 3.0869x over previous
//
#include <hip/hip_runtime.h>
#include <math.h>

#define NB   16      // batch
#define NM   4096    // preds per image
#define NT   512     // targets per image
#define CAP  16      // max candidates per row (overflow -> exact fallback)
#define IOU_THR 0.1f
#define EPSG 1e-7f
#define NROWS (NB*NM)
#define T_WIN 512            // threads per auction block
#define NWIN  (NM / T_WIN)   // 8 ascending windows, 1 row/thread/window
#define SENT  0xFFFFFFFFu

// ---------------------------------------------------------------------------
// Kernel 1: wave-per-row candidate build, targets staged in LDS per 64-row
// block. Ballot compaction, ascending-j order, transposed (e-major) storage
// so kernel-2's per-window register prefetch is coalesced.  (R8, measured.)
// ---------------------------------------------------------------------------
__global__ __launch_bounds__(256) void cand_kernel(
    const float4* __restrict__ pred, const float4* __restrict__ tgt,
    int* __restrict__ counts, float2* __restrict__ cands)
{
    __shared__ float4 t_lds[NT];
    const int rb = blockIdx.x * 64;          // 64 rows per block, same image
    const int b  = rb >> 12;                 // NM = 4096
    for (int i = threadIdx.x; i < NT; i += 256)
        t_lds[i] = tgt[b * NT + i];
    __syncthreads();

    const int wv = threadIdx.x >> 6, lane = threadIdx.x & 63;
    for (int rr = 0; rr < 16; ++rr) {
        const int row = rb + wv * 16 + rr;
        float4 p = pred[row];                // wave-uniform load
        float area_p = (p.z - p.x) * (p.w - p.y);
        int base = 0;
        #pragma unroll
        for (int pass = 0; pass < NT / 64; ++pass) {
            int j = (pass << 6) + lane;
            float4 t = t_lds[j];
            float area_t = (t.z - t.x) * (t.w - t.y);
            float w = fmaxf(fminf(p.z, t.z) - fmaxf(p.x, t.x), 0.f);
            float h = fmaxf(fminf(p.w, t.w) - fmaxf(p.y, t.y), 0.f);
            float inter = w * h;
            float uni   = (area_p + area_t) - inter;   // ref association
            float iou   = inter / uni;
            bool q = iou > IOU_THR;
            unsigned long long m = __ballot(q);
            if (q) {
                int off = base + __popcll(m & ((1ull << lane) - 1ull));
                if (off < CAP)
                    cands[(size_t)off * NROWS + row] = make_float2(iou, __int_as_float(j));
            }
            base += __popcll(m);
        }
        if (lane == 0) counts[row] = base;   // > CAP flags overflow
    }
}

// ---------------------------------------------------------------------------
// Kernel 2: windowed auction, 512 threads/image, 1 row per thread per window.
// Ascending windows resolved to their internal fixed point are FINAL (claim
// influence flows strictly upward in row index). Per round: recheck + register
// scan + atomicMin immediate-settle + ONE barrier (monotone lastprop stamp —
// no flag reset, no race). claim[j] = min proposer (monotone) -> unique fixed
// point == serial greedy. Commit by target at the end.
// ---------------------------------------------------------------------------
__global__ __launch_bounds__(T_WIN) void win_auction(
    const float4* __restrict__ pred, const float4* __restrict__ tgt,
    const int* __restrict__ counts, const float2* __restrict__ cands,
    float* __restrict__ per_img)
{
    __shared__ float4   t_lds[NT];       // 8 KB
    __shared__ unsigned claim[NT];       // 2 KB
    __shared__ int lastprop;             // monotone round stamp
    __shared__ unsigned char winovf[NWIN];
    __shared__ int ovf_min, ovf_res;
    __shared__ float rvv[T_WIN / 64];  __shared__ int rjj[T_WIN / 64];
    __shared__ float rls[T_WIN / 64];  __shared__ float rcs[T_WIN / 64];

    const int b = blockIdx.x, t = threadIdx.x, gbase = b * NM;
    const int wv = t >> 6, lane = t & 63;

    t_lds[t] = tgt[b * NT + t];
    claim[t] = SENT;
    if (t < NWIN) winovf[t] = 0;
    if (t == 0) lastprop = -1;
    __syncthreads();

    // all counts up front (8 coalesced loads), flag overflow windows
    int allCnt[NWIN];
    #pragma unroll
    for (int k = 0; k < NWIN; ++k) {
        allCnt[k] = counts[gbase + k * T_WIN + t];
        if (allCnt[k] > CAP) winovf[k] = 1;
    }
    // prefetch window 0 candidates into registers
    float2 nC[CAP];
    #pragma unroll
    for (int e = 0; e < CAP; ++e) nC[e] = cands[(size_t)e * NROWS + gbase + t];
    __syncthreads();                      // winovf visible to all

    int rglob = 0;
    float2 cC[CAP];
    for (int w = 0; w < NWIN; ++w) {
        #pragma unroll
        for (int e = 0; e < CAP; ++e) cC[e] = nC[e];
        const int cCnt = allCnt[w];
        if (w + 1 < NWIN) {               // prefetch next window; hides under rounds
            #pragma unroll
            for (int e = 0; e < CAP; ++e)
                nC[e] = cands[(size_t)e * NROWS + gbase + (w + 1) * T_WIN + t];
        }
        const unsigned row = (unsigned)(w * T_WIN + t);
        int  stt  = (cCnt > 0 && cCnt <= CAP) ? 0 : 2;   // 0=UNRES 1=HOLD 2=DONE
        int  myj  = -1;
        bool isovf = (cCnt > CAP);
        int  ovfj  = -1;

        for (;;) {
            // ---- auction rounds to window fixed point (1 barrier/round) ----
            for (;;) {
                if (stt == 1 && claim[myj] != row) stt = 0;      // sniped: rejoin
                bool did = false;
                if (stt == 0) {
                    for (int it = 0; it <= CAP; ++it) {          // bounded retry
                        float bv = -1.f; int bj = -1;
                        #pragma unroll
                        for (int e = 0; e < CAP; ++e) {          // independent reads
                            float2 ce = cC[e];
                            int j = __float_as_int(ce.y) & (NT - 1);
                            unsigned cj = claim[j];
                            if (e < cCnt && cj >= row && ce.x > bv) { bv = ce.x; bj = j; }
                        }
                        if (bj < 0) { stt = 2; break; }          // invalid (permanent)
                        did = true;
                        unsigned old = atomicMin(&claim[bj], row);
                        if (old >= row) { myj = bj; stt = 1; break; }   // settled
                        // lost: claim[bj] < row is permanent -> excluded next scan
                    }
                }
                if (did) lastprop = rglob;    // benign: all writers store same value
                __syncthreads();
                int lp = lastprop;
                ++rglob;
                if (lp < rglob - 1) break;    // no proposal this round: fixed point
            }
            // ---- overflow fallback (count > CAP, ~never) ----
            if (!winovf[w]) break;
            if (t == 0) ovf_min = 0x7FFFFFFF;
            __syncthreads();
            bool pend = isovf && (ovfj < 0 || claim[ovfj] != row);
            if (pend) atomicMin(&ovf_min, (int)row);
            __syncthreads();
            const int rowF = ovf_min;                            // uniform
            if (rowF == 0x7FFFFFFF) break;                       // window done
            {   // exact claim-aware argmax over all 512 targets (thread t = target t)
                float4 p4 = pred[gbase + rowF];                  // uniform address
                float4 tt = t_lds[t];
                float area_p = (p4.z - p4.x) * (p4.w - p4.y);
                float area_t = (tt.z - tt.x) * (tt.w - tt.y);
                float wd = fmaxf(fminf(p4.z, tt.z) - fmaxf(p4.x, tt.x), 0.f);
                float hd = fmaxf(fminf(p4.w, tt.w) - fmaxf(p4.y, tt.y), 0.f);
                float inter = wd * hd;
                float iou = inter / ((area_p + area_t) - inter);
                bool freej = claim[t] > (unsigned)rowF;          // smaller = final-used
                float v = freej ? iou : -1.f;
                int bj = freej ? t : NT;
                #pragma unroll
                for (int off = 1; off < 64; off <<= 1) {
                    float ov = __shfl_xor(v, off);
                    int   oj = __shfl_xor(bj, off);
                    if (ov > v || (ov == v && oj < bj)) { v = ov; bj = oj; }
                }
                if (lane == 0) { rvv[wv] = v; rjj[wv] = bj; }
            }
            __syncthreads();
            if (t == 0) {
                float v = rvv[0]; int bj = rjj[0];
                for (int q = 1; q < T_WIN / 64; ++q)
                    if (rvv[q] > v || (rvv[q] == v && rjj[q] < bj)) { v = rvv[q]; bj = rjj[q]; }
                if (v > IOU_THR) { ovf_res = bj; claim[bj] = (unsigned)rowF; }  // steal
                else ovf_res = -1;
            }
            __syncthreads();
            if ((int)row == rowF) {
                if (ovf_res >= 0) ovfj = ovf_res;   // matched (recorded in claim)
                else isovf = false;                 // permanently invalid
            }
            // displaced holder (if any) re-detected at next round's recheck
        }
    }
    __syncthreads();

    // ---- commit by target: claim[j]==r <=> r matched j (unique fixed point) ----
    float ls = 0.f, cs = 0.f;
    {
        unsigned r = claim[t];
        if (r != SENT) {
            float4 p4 = pred[gbase + (int)r];
            float4 tt = t_lds[t];
            float inter = fmaxf(fminf(p4.z, tt.z) - fmaxf(p4.x, tt.x), 0.f) *
                          fmaxf(fminf(p4.w, tt.w) - fmaxf(p4.y, tt.y), 0.f);
            float area_p = (p4.z - p4.x) * (p4.w - p4.y);
            float area_t = (tt.z - tt.x) * (tt.w - tt.y);
            float uni = area_p + area_t - inter;
            float iou = inter / (uni + EPSG);
            float enc = (fmaxf(p4.z, tt.z) - fminf(p4.x, tt.x)) *
                        (fmaxf(p4.w, tt.w) - fminf(p4.y, tt.y));
            float giou = iou - (enc - uni) / (enc + EPSG);
            ls = 1.f - giou;
            cs = 1.f;
        }
    }
    #pragma unroll
    for (int off = 32; off >= 1; off >>= 1) {
        ls += __shfl_xor(ls, off);
        cs += __shfl_xor(cs, off);
    }
    if (lane == 0) { rls[wv] = ls; rcs[wv] = cs; }
    __syncthreads();
    if (t == 0) {
        float L = 0.f, C = 0.f;
        for (int q = 0; q < T_WIN / 64; ++q) { L += rls[q]; C += rcs[q]; }
        per_img[b] = (C > 0.f) ? L / C : 0.f;
    }
}

// ---------------------------------------------------------------------------
// Kernel 3: mean over images -> scalar output. Deterministic (no atomics).
// ---------------------------------------------------------------------------
__global__ void reduce_kernel(const float* __restrict__ per_img,
                              float* __restrict__ out)
{
    if (threadIdx.x == 0 && blockIdx.x == 0) {
        float s = 0.f;
        for (int i = 0; i < NB; ++i) s += per_img[i];
        out[0] = s / (float)NB;
    }
}

extern "C" void kernel_launch(void* const* d_in, const int* in_sizes, int n_in,
                              void* d_out, int out_size, void* d_ws, size_t ws_size,
                              hipStream_t stream)
{
    const float4* pred = (const float4*)d_in[0];   // [16,4096,4] f32
    const float4* tgt  = (const float4*)d_in[1];   // [16,512,4]  f32

    char* ws = (char*)d_ws;
    // layout: counts [NROWS] i32 | cands [CAP*NROWS] float2 | per_img [NB] f32
    int*    counts  = (int*)ws;
    size_t  off1    = (size_t)NROWS * sizeof(int);                 // 256 KB
    float2* cands   = (float2*)(ws + off1);
    size_t  off2    = off1 + (size_t)CAP * NROWS * sizeof(float2); // +8 MB
    float*  per_img = (float*)(ws + off2);

    cand_kernel<<<NROWS / 64, 256, 0, stream>>>(pred, tgt, counts, cands);
    win_auction<<<NB, T_WIN, 0, stream>>>(pred, tgt, counts, cands, per_img);
    reduce_kernel<<<1, 64, 0, stream>>>(per_img, (float*)d_out);
}